// Round 1
// baseline (262.549 us; speedup 1.0000x reference)
//
#include <hip/hip_runtime.h>

#define NC   8
#define NN   256
#define MTOT 17408   // NSPOKE*NVEC = 34*512

typedef __attribute__((ext_vector_type(8))) short short8;
typedef __attribute__((ext_vector_type(4))) float f32x4;

static __device__ __forceinline__ short f2bf(float f) {
    union { float f; unsigned u; } v; v.f = f;
    return (short)((v.u + 0x7fffu + ((v.u >> 16) & 1u)) >> 16);
}

// K1: src[c][a][b] = (Xr + i Xi) * (Cr + i Ci) -> bf16 planes Sr, Si
__global__ __launch_bounds__(256) void build_src(
        const float* __restrict__ X, const float* __restrict__ C,
        short* __restrict__ Sr, short* __restrict__ Si) {
    int idx = blockIdx.x * 256 + threadIdx.x;   // [0, 8*65536)
    int ab = idx & 65535;
    float xr = X[ab * 2 + 0], xi = X[ab * 2 + 1];
    float cr = C[idx * 2 + 0], ci = C[idx * 2 + 1];
    Sr[idx] = f2bf(xr * cr - xi * ci);
    Si[idx] = f2bf(xr * ci + xi * cr);
}

// K2: y[c,k] = sum_a Ea[k,a] * sum_b src[c,a,b] * Eb[k,b], scaled by w[k].
// GEMM view per (c, k-tile): A = src[c] (M=256 a x K=256 b, complex bf16),
// B = Eb^T (K=256 b x N=16 k per wave, complex, generated in registers),
// epilogue reduces M with Ea weights.
__global__ __launch_bounds__(256) void nufft_fwd(
        const float* __restrict__ angles, const float* __restrict__ w,
        const short* __restrict__ SrP, const short* __restrict__ SiP,
        float* __restrict__ out) {
    const int lane = threadIdx.x & 63;
    const int wv   = threadIdx.x >> 6;
    const int c    = blockIdx.y;
    const int col  = lane & 15;       // MFMA: A-row / D-col index
    const int grp  = lane >> 4;       // MFMA: K-group / D-row-group
    const int kglob = blockIdx.x * 64 + wv * 16 + col;

    const float s = angles[kglob * 2 + 0];
    const float t = angles[kglob * 2 + 1];

    // Generate B fragments (Eb = exp(-i * t * x_b), x_b = b-128) in registers.
    // B-frag layout (16x16x32): n = lane&15, k(b) = (lane>>4)*8 + j.
    short8 Br[8], Bi[8];
    #pragma unroll
    for (int bs = 0; bs < 8; ++bs) {
        short8 re, im;
        #pragma unroll
        for (int j = 0; j < 8; ++j) {
            float xb = (float)(bs * 32 + grp * 8 + j - 128);
            float sn, cs;
            __sincosf(t * xb, &sn, &cs);
            re[j] = f2bf(cs);
            im[j] = f2bf(-sn);
        }
        Br[bs] = re; Bi[bs] = im;
    }

    const short* Ar0 = SrP + c * 65536;
    const short* Ai0 = SiP + c * 65536;

    float yr = 0.f, yi = 0.f;
    for (int at = 0; at < 16; ++at) {
        f32x4 P1 = {0.f,0.f,0.f,0.f}, P2 = {0.f,0.f,0.f,0.f};
        f32x4 P3 = {0.f,0.f,0.f,0.f}, P4 = {0.f,0.f,0.f,0.f};
        // A-frag: row m = at*16 + (lane&15), k(b) = bs*32 + (lane>>4)*8 + j
        const short* ar = Ar0 + (at * 16 + col) * 256 + grp * 8;
        const short* ai = Ai0 + (at * 16 + col) * 256 + grp * 8;
        #pragma unroll
        for (int bs = 0; bs < 8; ++bs) {
            short8 Arf = *(const short8*)(ar + bs * 32);
            short8 Aif = *(const short8*)(ai + bs * 32);
            P1 = __builtin_amdgcn_mfma_f32_16x16x32_bf16(Arf, Br[bs], P1, 0, 0, 0);
            P2 = __builtin_amdgcn_mfma_f32_16x16x32_bf16(Aif, Bi[bs], P2, 0, 0, 0);
            P3 = __builtin_amdgcn_mfma_f32_16x16x32_bf16(Arf, Bi[bs], P3, 0, 0, 0);
            P4 = __builtin_amdgcn_mfma_f32_16x16x32_bf16(Aif, Br[bs], P4, 0, 0, 0);
        }
        // Epilogue: D layout col = lane&15 (k), row = (lane>>4)*4 + r (a).
        int a0 = at * 16 + grp * 4;
        #pragma unroll
        for (int r = 0; r < 4; ++r) {
            float Tr = P1[r] - P2[r];
            float Ti = P3[r] + P4[r];
            float sn, cs;
            __sincosf(s * (float)(a0 + r - 128), &sn, &cs);
            // Ea = cs - i*sn ; y += Ea * T
            yr += cs * Tr + sn * Ti;
            yi += cs * Ti - sn * Tr;
        }
    }
    // Reduce the 4 lane-groups (same k, disjoint a-rows).
    yr += __shfl_xor(yr, 16); yr += __shfl_xor(yr, 32);
    yi += __shfl_xor(yi, 16); yi += __shfl_xor(yi, 32);

    if (grp == 0) {
        float wk = w[kglob];
        out[(c * MTOT + kglob) * 2 + 0] = yr * wk;
        out[(c * MTOT + kglob) * 2 + 1] = yi * wk;
    }
}

extern "C" void kernel_launch(void* const* d_in, const int* in_sizes, int n_in,
                              void* d_out, int out_size, void* d_ws, size_t ws_size,
                              hipStream_t stream) {
    const float* X      = (const float*)d_in[0];
    const float* angles = (const float*)d_in[1];
    const float* C      = (const float*)d_in[2];
    const float* w      = (const float*)d_in[3];
    float* out = (float*)d_out;

    short* Sr = (short*)d_ws;            // NC*256*256 bf16 = 1 MB
    short* Si = Sr + NC * 65536;         // +1 MB

    build_src<<<dim3(NC * 65536 / 256), dim3(256), 0, stream>>>(X, C, Sr, Si);

    dim3 grid(MTOT / 64, NC);            // (272, 8)
    nufft_fwd<<<grid, dim3(256), 0, stream>>>(angles, w, Sr, Si, out);
}

// Round 2
// 90.219 us; speedup vs baseline: 2.9101x; 2.9101x over previous
//
#include <hip/hip_runtime.h>

#define NC   8
#define MTOT 17408   // NSPOKE*NVEC = 34*512

typedef __attribute__((ext_vector_type(8))) short short8;
typedef __attribute__((ext_vector_type(4))) float f32x4;

typedef __attribute__((address_space(3))) unsigned       lds_uint;
typedef const __attribute__((address_space(1))) unsigned glb_uint;

static __device__ __forceinline__ short f2bf(float f) {
    union { float f; unsigned u; } v; v.f = f;
    return (short)((v.u + 0x7fffu + ((v.u >> 16) & 1u)) >> 16);
}

// K1: src[c][a][b] = (Xr + i Xi) * (Cr + i Ci) -> bf16 planes Sr, Si
__global__ __launch_bounds__(256) void build_src(
        const float* __restrict__ X, const float* __restrict__ C,
        short* __restrict__ Sr, short* __restrict__ Si) {
    int idx = blockIdx.x * 256 + threadIdx.x;   // [0, 8*65536)
    int ab = idx & 65535;
    float xr = X[ab * 2 + 0], xi = X[ab * 2 + 1];
    float cr = C[idx * 2 + 0], ci = C[idx * 2 + 1];
    Sr[idx] = f2bf(xr * cr - xi * ci);
    Si[idx] = f2bf(xr * ci + xi * cr);
}

// K2: y[c,k] = sum_a Ea[k,a] * sum_b src[c,a,b] * Eb[k,b], scaled by w[k].
// Block = (64 k-cols, coil). A-tiles (16 a-rows x 256 b, 2 planes) staged in
// LDS via global_load_lds (double-buffered), shared by the 4 waves.
// LDS layout per half (16KB): byte = plane*8192 + row*512 + slot*16,
// slot = chunk ^ (row&7)  (XOR swizzle; source pre-swizzled, rule #21).
__global__ __launch_bounds__(256) void nufft_fwd(
        const float* __restrict__ angles, const float* __restrict__ w,
        const short* __restrict__ SrP, const short* __restrict__ SiP,
        float* __restrict__ out) {
    __shared__ char lds[32768];

    const int lane = threadIdx.x & 63;
    const int wv   = threadIdx.x >> 6;
    const int c    = blockIdx.y;
    const int col  = lane & 15;       // MFMA: A-row / D-col index
    const int grp  = lane >> 4;       // MFMA: K-group / D-row-group
    const int kglob = blockIdx.x * 64 + wv * 16 + col;

    const float s = angles[kglob * 2 + 0];
    const float t = angles[kglob * 2 + 1];

    const short* Sr = SrP + c * 65536;
    const short* Si = SiP + c * 65536;

    // B fragments (Eb = exp(-i * t * x_b), x_b = b-128) in registers.
    // B-frag layout (16x16x32): n = lane&15, k(b) = (lane>>4)*8 + j.
    short8 Br[8], Bi[8];
    #pragma unroll
    for (int bs = 0; bs < 8; ++bs) {
        short8 re, im;
        #pragma unroll
        for (int j = 0; j < 8; ++j) {
            float xb = (float)(bs * 32 + grp * 8 + j - 128);
            float sn, cs;
            __sincosf(t * xb, &sn, &cs);
            re[j] = f2bf(cs);
            im[j] = f2bf(-sn);
        }
        Br[bs] = re; Bi[bs] = im;
    }

    // Stage a-tile `at` into LDS half `half` (16KB = 1024 x 16B chunks,
    // 4 chunks per thread). Global source pre-swizzled so linear
    // global_load_lds dest + swizzled ds_read agree.
    auto stage = [&](int at, int half) {
        #pragma unroll
        for (int it = 0; it < 4; ++it) {
            int L   = it * 256 + wv * 64 + lane;     // linear 16B-chunk id
            int row = (L >> 5) & 15;
            int cb  = (L & 31) ^ (row & 7);          // global chunk for this slot
            const short* g = ((L >> 9) ? Si : Sr) + (at * 16 + row) * 256 + cb * 8;
            __builtin_amdgcn_global_load_lds(
                (glb_uint*)g,
                (lds_uint*)(lds + half * 16384 + it * 4096 + wv * 1024),
                16, 0, 0);
        }
    };

    float yr = 0.f, yi = 0.f;

    stage(0, 0);
    __syncthreads();                 // drains vmcnt before first compute

    for (int at = 0; at < 16; ++at) {
        const int cur = at & 1;
        if (at < 15) stage(at + 1, cur ^ 1);

        const char* buf = lds + cur * 16384;
        f32x4 P1 = {0.f,0.f,0.f,0.f}, P2 = {0.f,0.f,0.f,0.f};
        f32x4 P3 = {0.f,0.f,0.f,0.f}, P4 = {0.f,0.f,0.f,0.f};
        const int rowoff = col * 512;
        const int swz    = col & 7;
        #pragma unroll
        for (int bs = 0; bs < 8; ++bs) {
            int cbp = ((grp | (bs << 2)) ^ swz) << 4;
            short8 Arf = *(const short8*)(buf + rowoff + cbp);
            short8 Aif = *(const short8*)(buf + 8192 + rowoff + cbp);
            P1 = __builtin_amdgcn_mfma_f32_16x16x32_bf16(Arf, Br[bs], P1, 0, 0, 0);
            P2 = __builtin_amdgcn_mfma_f32_16x16x32_bf16(Aif, Bi[bs], P2, 0, 0, 0);
            P3 = __builtin_amdgcn_mfma_f32_16x16x32_bf16(Arf, Bi[bs], P3, 0, 0, 0);
            P4 = __builtin_amdgcn_mfma_f32_16x16x32_bf16(Aif, Br[bs], P4, 0, 0, 0);
        }
        // Epilogue: D layout col = lane&15 (k), row = (lane>>4)*4 + r (a).
        int a0 = at * 16 + grp * 4;
        #pragma unroll
        for (int r = 0; r < 4; ++r) {
            float Tr = P1[r] - P2[r];
            float Ti = P3[r] + P4[r];
            float sn, cs;
            __sincosf(s * (float)(a0 + r - 128), &sn, &cs);
            yr += cs * Tr + sn * Ti;   // Ea = cs - i*sn ; y += Ea * T
            yi += cs * Ti - sn * Tr;
        }
        __syncthreads();   // drains next-tile vmcnt + protects buffer reuse
    }

    // Reduce the 4 lane-groups (same k, disjoint a-rows).
    yr += __shfl_xor(yr, 16); yr += __shfl_xor(yr, 32);
    yi += __shfl_xor(yi, 16); yi += __shfl_xor(yi, 32);

    if (grp == 0) {
        float wk = w[kglob];
        out[(c * MTOT + kglob) * 2 + 0] = yr * wk;
        out[(c * MTOT + kglob) * 2 + 1] = yi * wk;
    }
}

extern "C" void kernel_launch(void* const* d_in, const int* in_sizes, int n_in,
                              void* d_out, int out_size, void* d_ws, size_t ws_size,
                              hipStream_t stream) {
    const float* X      = (const float*)d_in[0];
    const float* angles = (const float*)d_in[1];
    const float* C      = (const float*)d_in[2];
    const float* w      = (const float*)d_in[3];
    float* out = (float*)d_out;

    short* Sr = (short*)d_ws;            // NC*256*256 bf16 = 1 MB
    short* Si = Sr + NC * 65536;         // +1 MB

    build_src<<<dim3(NC * 65536 / 256), dim3(256), 0, stream>>>(X, C, Sr, Si);

    dim3 grid(MTOT / 64, NC);            // (272, 8)
    nufft_fwd<<<grid, dim3(256), 0, stream>>>(angles, w, Sr, Si, out);
}